// Round 21
// baseline (275.210 us; speedup 1.0000x reference)
//
#include <hip/hip_runtime.h>
#include <hip/hip_bf16.h>

#define T_TOK 4096
#define DDIM  1024
#define HDIM  2048
#define NEXP  8
#define MAXSLOT 9216   // 2T padded: each expert base 128-aligned

typedef __attribute__((ext_vector_type(4))) float f32x4;
typedef __attribute__((ext_vector_type(8))) short s16x8;
typedef __hip_bfloat16 bf16;

typedef const void __attribute__((address_space(1))) gvoid;
typedef void __attribute__((address_space(3))) svoid;

__device__ __forceinline__ void gload16(const void* g, void* l) {
    // async global->LDS, 16B/lane; LDS dest = wave-uniform base, HW adds lane*16
    __builtin_amdgcn_global_load_lds((gvoid*)g, (svoid*)l, 16, 0, 0);
}

// Conflict-free transpose tile swizzle (R16-proven): elem (r,c) at
// r*64 + 4*((c>>2) ^ sw(r)) + (c&3), sw(r) = ((r>>2) ^ ((r&3)<<2)) & 15.
__device__ __forceinline__ int sw_r(int r) { return ((r >> 2) ^ ((r & 3) << 2)) & 15; }

// ======== prep: wg/wu transposes + router + x-cast + y-zero (wd lives in gateup) ====
// blocks [0,8192): wg/wu transpose -> wguT interleaved
// blocks [8192,9216): router (fp64 acc top-2 softmax) + x->bf16 cast + y-zero
__global__ void prep_kernel(const float* __restrict__ x, const float* __restrict__ rw,
                            const float* __restrict__ wg, const float* __restrict__ wu,
                            bf16* __restrict__ wguT,
                            int* __restrict__ r_e, float* __restrict__ r_w,
                            bf16* __restrict__ xb, float* __restrict__ y) {
    int bid = blockIdx.x;
    int tid = threadIdx.x;

    if (bid >= 8192) {
        // ---- router + cast + y-zero ----
        int rb = bid - 8192;                   // [0,1024)
        {
            float4 z4 = {0.f, 0.f, 0.f, 0.f};
            size_t ybase = (size_t)rb * 4096 + tid * 4;
#pragma unroll
            for (int i = 0; i < 4; ++i)
                *reinterpret_cast<float4*>(y + ybase + (size_t)i * 1024) = z4;
        }
        int wave = tid >> 6, lane = tid & 63;
        int t = rb * 4 + wave;
        const float* xr = x + (size_t)t * DDIM;
        bf16* xbr = xb + (size_t)t * DDIM;
        double acc[NEXP];
#pragma unroll
        for (int e = 0; e < NEXP; ++e) acc[e] = 0.0;
#pragma unroll
        for (int c = 0; c < 4; ++c) {
            int d = c * 256 + lane * 4;
            float4 v = *reinterpret_cast<const float4*>(xr + d);
            union { ushort4 u; bf16 h[4]; } o;
            o.h[0] = __float2bfloat16(v.x);
            o.h[1] = __float2bfloat16(v.y);
            o.h[2] = __float2bfloat16(v.z);
            o.h[3] = __float2bfloat16(v.w);
            *reinterpret_cast<ushort4*>(xbr + d) = o.u;
            const float* rw0 = rw + (size_t)d * NEXP;
#pragma unroll
            for (int j = 0; j < 4; ++j) {
                float xv = (&v.x)[j];
                const float* rwr = rw0 + j * NEXP;
#pragma unroll
                for (int e = 0; e < NEXP; ++e) acc[e] += (double)xv * (double)rwr[e];
            }
        }
#pragma unroll
        for (int e = 0; e < NEXP; ++e) {
#pragma unroll
            for (int off = 32; off > 0; off >>= 1) acc[e] += __shfl_down(acc[e], off);
        }
        if (lane == 0) {
            int i0 = 0; double v0 = acc[0];
#pragma unroll
            for (int e = 1; e < NEXP; ++e) if (acc[e] > v0) { v0 = acc[e]; i0 = e; }
            int i1 = -1; double v1 = -1e300;
#pragma unroll
            for (int e = 0; e < NEXP; ++e) { if (e == i0) continue; if (acc[e] > v1) { v1 = acc[e]; i1 = e; } }
            float w0 = 1.0f / (1.0f + expf((float)(v1 - v0)));
            float w1 = 1.0f - w0;
            r_e[2*t]   = i0; r_e[2*t+1] = i1;
            r_w[2*t]   = w0; r_w[2*t+1] = w1;
        }
        return;
    }

    // ---- wg/wu transpose ----
    __shared__ __align__(16) bf16 tile[64 * 64];
    int z = bid >> 9;              // [0,16)
    int t = bid & 511;
    int which = z >> 3, e = z & 7;
    const float* inp = (which ? wu : wg) + (size_t)e * DDIM * HDIM;   // [D][H]
    bf16* outp = wguT + (size_t)e * 2 * HDIM * DDIM + (size_t)which * DDIM;
    int r0 = (t >> 5) * 64;        // 16 r-tiles over D
    int c0 = (t & 31) * 64;        // 32 c-tiles over H
#pragma unroll
    for (int i = 0; i < 4; ++i) {
        int idx = i * 256 + tid;
        int r = idx >> 4, c4 = (idx & 15) * 4;
        float4 v = *reinterpret_cast<const float4*>(inp + (size_t)(r0 + r) * HDIM + c0 + c4);
        union { ushort4 u; bf16 h[4]; } o;
        o.h[0] = __float2bfloat16(v.x);
        o.h[1] = __float2bfloat16(v.y);
        o.h[2] = __float2bfloat16(v.z);
        o.h[3] = __float2bfloat16(v.w);
        *reinterpret_cast<ushort4*>(&tile[r * 64 + 4 * ((c4 >> 2) ^ sw_r(r))]) = o.u;
    }
    __syncthreads();
#pragma unroll
    for (int i = 0; i < 4; ++i) {
        int idx = i * 256 + tid;
        int c = idx >> 4, r4 = (idx & 15) * 4;
        int g = c >> 2, ce = c & 3;
        union { ushort4 u; bf16 h[4]; } w;
#pragma unroll
        for (int j = 0; j < 4; ++j) {
            int r = r4 + j;
            w.h[j] = tile[r * 64 + 4 * (g ^ sw_r(r)) + ce];
        }
        *reinterpret_cast<ushort4*>(outp + (size_t)(c0 + c) * (2 * DDIM) + r0 + r4) = w.u;
    }
}

// ------- fused binning: count + 128-ALIGNED scan + fill, one block, 1024 thr -------
__global__ void binning_kernel(const int* __restrict__ r_e, const float* __restrict__ r_w,
                               int* __restrict__ offs, int* __restrict__ cnt,
                               int* __restrict__ list, float* __restrict__ slot_w) {
    __shared__ int scnt[NEXP], scur[NEXP], soff[NEXP + 1];
    int tid = threadIdx.x;
    if (tid < NEXP) { scnt[tid] = 0; scur[tid] = 0; }
    __syncthreads();
    for (int i = tid; i < 2 * T_TOK; i += 1024) atomicAdd(&scnt[r_e[i]], 1);
    __syncthreads();
    if (tid == 0) {
        int s = 0;
        for (int e = 0; e < NEXP; ++e) { soff[e] = s; s += (scnt[e] + 127) & ~127; }
        soff[NEXP] = s;
    }
    __syncthreads();
    if (tid < NEXP + 1) offs[tid] = soff[tid];
    if (tid < NEXP) cnt[tid] = scnt[tid];
    for (int i = tid; i < 2 * T_TOK; i += 1024) {
        int e = r_e[i];
        int pos = atomicAdd(&scur[e], 1);
        int slot = soff[e] + pos;
        list[slot] = i >> 1;
        slot_w[slot] = r_w[i];
    }
}

// expert lookup in padded slot space
__device__ __forceinline__ int find_expert(const int* offs, int slot0) {
    int e = 0;
#pragma unroll
    for (int i = 0; i < NEXP - 1; ++i) e += (offs[e + 1] <= slot0) ? 1 : 0;
    return e;
}

// ======== pass 1: gate+up GEMM  +  INTERLEAVED piggybacked wd transpose ========
// Grid y in [0,136): 8 groups of 17 = {9 GEMM rows + 8 wd rows}, so every
// dispatch wave carries the ~9:8 GEMM:transpose mix (HBM slack consumed from
// wave 0 instead of back-loaded). GEMM: R4/R15 geometry (best-measured):
// 128(M) x 128(N-in-2H), BK=64, 8 waves (2M x 4N, acc[4][2]), 64 KB dbuf,
// counted vmcnt(4). wd path: 2 x 64x64 tiles/block, conflict-free swizzle.
__global__ __launch_bounds__(512, 2)
void gateup_kernel(const bf16* __restrict__ xb, const bf16* __restrict__ wguT,
                   const int* __restrict__ offs, const int* __restrict__ cnt,
                   const int* __restrict__ list, bf16* __restrict__ hbuf,
                   const float* __restrict__ wd, bf16* __restrict__ wdT) {
    __shared__ bf16 As[2][8192];     // GEMM: 128 rows x 64 k (16 KB/buf); wd path reuses 8 KB
    __shared__ bf16 Bs[2][8192];

    int tid = threadIdx.x;
    int grp = blockIdx.y / 17, rem = blockIdx.y % 17;

    if (rem >= 9) {
        // ---- wd transpose path: 2 tiles of 64x64 per block ----
        int wdid = (grp * 8 + (rem - 9)) * 32 + blockIdx.x;   // [0,2048)
        bf16* tile = &As[0][0];
#pragma unroll
        for (int tt = 0; tt < 2; ++tt) {
            int tb = wdid * 2 + tt;            // [0,4096)
            int e = tb >> 9;
            int t = tb & 511;
            const float* inp = wd + (size_t)e * HDIM * DDIM;     // [H][D]
            bf16* outp = wdT + (size_t)e * DDIM * HDIM;
            int r0 = (t >> 4) * 64;            // 32 r-tiles over H
            int c0 = (t & 15) * 64;            // 16 c-tiles over D
#pragma unroll
            for (int i = 0; i < 2; ++i) {
                int idx = i * 512 + tid;       // [0,1024)
                int r = idx >> 4, c4 = (idx & 15) * 4;
                float4 v = *reinterpret_cast<const float4*>(inp + (size_t)(r0 + r) * DDIM + c0 + c4);
                union { ushort4 u; bf16 h[4]; } o;
                o.h[0] = __float2bfloat16(v.x);
                o.h[1] = __float2bfloat16(v.y);
                o.h[2] = __float2bfloat16(v.z);
                o.h[3] = __float2bfloat16(v.w);
                *reinterpret_cast<ushort4*>(&tile[r * 64 + 4 * ((c4 >> 2) ^ sw_r(r))]) = o.u;
            }
            __syncthreads();
#pragma unroll
            for (int i = 0; i < 2; ++i) {
                int idx = i * 512 + tid;
                int c = idx >> 4, r4 = (idx & 15) * 4;
                int g = c >> 2, ce = c & 3;
                union { ushort4 u; bf16 h[4]; } w;
#pragma unroll
                for (int j = 0; j < 4; ++j) {
                    int r = r4 + j;
                    w.h[j] = tile[r * 64 + 4 * (g ^ sw_r(r)) + ce];
                }
                *reinterpret_cast<ushort4*>(outp + (size_t)(c0 + c) * HDIM + r0 + r4) = w.u;
            }
            __syncthreads();                   // tile buffer reuse
        }
        return;
    }

    // ---- GEMM path (R15-proven, frozen) ----
    int slot0 = (grp * 9 + rem) * 128;
    if (slot0 >= offs[NEXP]) return;
    int e = find_expert(offs, slot0);
    int base = offs[e];
    int ne = cnt[e];
    int m0 = slot0 - base;
    int n0 = blockIdx.x * 128;       // in 2H=4096 interleaved space

    int lane = tid & 63, wid = tid >> 6;       // 8 waves
    int sub = lane >> 3;                       // 0..7
    int koff = 8 * ((lane & 7) ^ sub);         // inverse-swizzled source chunk (row&7 == sub)

    const bf16* bbase = wguT + (size_t)e * (2 * HDIM) * DDIM + (size_t)n0 * DDIM;

    const bf16* aS[2]; const bf16* bS[2];
    int sdst[2];
#pragma unroll
    for (int j = 0; j < 2; ++j) {
        int q = wid + j * 8;                   // 0..15
        int row = q * 8 + sub;                 // [0,128)
        int r = m0 + row; if (r > ne - 1) r = ne - 1;   // clamp: read-only, never stored
        aS[j] = xb + (size_t)list[base + r] * DDIM + koff;
        bS[j] = bbase + (size_t)row * DDIM + koff;
        sdst[j] = q * 512;                     // wave-uniform elem offset
    }

    int rl = lane & 15, kq = 8 * (lane >> 4);
    int wrow = (wid >> 2) * 64;      // 2 M waves
    int wcol = (wid & 3) * 32;       // 4 N waves
    int xorv = (rl & 7) * 8;         // read-side swizzle

    f32x4 zero4 = {0.f, 0.f, 0.f, 0.f};
    f32x4 acc[4][2];
#pragma unroll
    for (int mi = 0; mi < 4; ++mi) { acc[mi][0] = zero4; acc[mi][1] = zero4; }

    const int nk = DDIM / 64;   // 16

#define GU_STAGE(tt, buf)                                     \
    {                                                         \
        int k0 = (tt) * 64;                                   \
        gload16(aS[0] + k0, &As[buf][sdst[0]]);               \
        gload16(aS[1] + k0, &As[buf][sdst[1]]);               \
        gload16(bS[0] + k0, &Bs[buf][sdst[0]]);               \
        gload16(bS[1] + k0, &Bs[buf][sdst[1]]);               \
    }

#define GU_COMPUTE(Ab, Bb)                                                        \
    _Pragma("unroll")                                                             \
    for (int kk = 0; kk < 2; ++kk) {                                              \
        int kos = (kk * 32 + kq) ^ xorv;                                          \
        s16x8 a[4], b[2];                                                         \
        _Pragma("unroll")                                                         \
        for (int mi = 0; mi < 4; ++mi)                                            \
            a[mi] = *reinterpret_cast<const s16x8*>(&(Ab)[(wrow + mi * 16 + rl) * 64 + kos]); \
        _Pragma("unroll")                                                         \
        for (int ni = 0; ni < 2; ++ni)                                            \
            b[ni] = *reinterpret_cast<const s16x8*>(&(Bb)[(wcol + ni * 16 + rl) * 64 + kos]); \
        __builtin_amdgcn_s_setprio(1);                                            \
        _Pragma("unroll")                                                         \
        for (int mi = 0; mi < 4; ++mi)                                            \
            _Pragma("unroll")                                                     \
            for (int ni = 0; ni < 2; ++ni)                                        \
                acc[mi][ni] = __builtin_amdgcn_mfma_f32_16x16x32_bf16(a[mi], b[ni], acc[mi][ni], 0, 0, 0); \
        __builtin_amdgcn_s_setprio(0);                                            \
    }

    GU_STAGE(0, 0);
    GU_STAGE(1, 1);

    for (int t = 0; t < nk; ++t) {
        if (t + 1 < nk) asm volatile("s_waitcnt vmcnt(4)" ::: "memory");   // tile t landed
        else            asm volatile("s_waitcnt vmcnt(0)" ::: "memory");
        __builtin_amdgcn_s_barrier();
        GU_COMPUTE(As[t & 1], Bs[t & 1]);
        __builtin_amdgcn_sched_barrier(0);
        __builtin_amdgcn_s_barrier();                 // buf[t&1] free
        if (t + 2 < nk) GU_STAGE(t + 2, t & 1);       // in flight: t+1(4) + t+2(4)
    }
#undef GU_COMPUTE
#undef GU_STAGE

    // epilogue: even col = gate, odd col = up; pair via shfl_xor(1), even lanes store.
    int rbase = (lane >> 4) * 4, cbase = lane & 15;
    bool evenlane = (lane & 1) == 0;
#pragma unroll
    for (int mi = 0; mi < 4; ++mi) {
#pragma unroll
        for (int ni = 0; ni < 2; ++ni) {
#pragma unroll
            for (int r = 0; r < 4; ++r) {
                float own = acc[mi][ni][r];
                float oth = __shfl_xor(own, 1);
                int row = m0 + wrow + mi * 16 + rbase + r;
                if (evenlane && row < ne) {
                    float g = own, u = oth;
                    float h = (g / (1.0f + expf(-g))) * u;
                    int hcol = (n0 + wcol + ni * 16 + cbase) >> 1;
                    hbuf[(size_t)(base + row) * HDIM + hcol] = __float2bfloat16(h);
                }
            }
        }
    }
}

// ======== pass 2: down GEMM, R15 structure at 128x128, BK=64 (32 iters) ========
__global__ __launch_bounds__(512, 2)
void down_kernel(const bf16* __restrict__ hbuf, const bf16* __restrict__ wdT,
                 const int* __restrict__ offs, const int* __restrict__ cnt,
                 const int* __restrict__ list, const float* __restrict__ slot_w,
                 float* __restrict__ y) {
    int slot0 = blockIdx.y * 128;
    if (slot0 >= offs[NEXP]) return;
    int e = find_expert(offs, slot0);
    int base = offs[e];
    int ne = cnt[e];
    int m0 = slot0 - base;
    int n0 = blockIdx.x * 128;   // d-tile

    __shared__ bf16 As[2][8192];
    __shared__ bf16 Bs[2][8192];

    int tid = threadIdx.x, lane = tid & 63, wid = tid >> 6;
    int sub = lane >> 3;
    int koff = 8 * ((lane & 7) ^ sub);

    const bf16* bbase = wdT + (size_t)e * DDIM * HDIM + (size_t)n0 * HDIM;

    const bf16* aS[2]; const bf16* bS[2];
    int sdst[2];
#pragma unroll
    for (int j = 0; j < 2; ++j) {
        int q = wid + j * 8;
        int row = q * 8 + sub;
        int r = m0 + row; if (r > ne - 1) r = ne - 1;
        aS[j] = hbuf + (size_t)(base + r) * HDIM + koff;
        bS[j] = bbase + (size_t)row * HDIM + koff;
        sdst[j] = q * 512;
    }

    int rl = lane & 15, kq = 8 * (lane >> 4);
    int wrow = (wid >> 2) * 64;
    int wcol = (wid & 3) * 32;
    int xorv = (rl & 7) * 8;

    f32x4 zero4 = {0.f, 0.f, 0.f, 0.f};
    f32x4 acc[4][2];
#pragma unroll
    for (int mi = 0; mi < 4; ++mi) { acc[mi][0] = zero4; acc[mi][1] = zero4; }

    const int nk = HDIM / 64;   // 32

#define DN_STAGE(tt, buf)                                     \
    {                                                         \
        int k0 = (tt) * 64;                                   \
        gload16(aS[0] + k0, &As[buf][sdst[0]]);               \
        gload16(aS[1] + k0, &As[buf][sdst[1]]);               \
        gload16(bS[0] + k0, &Bs[buf][sdst[0]]);               \
        gload16(bS[1] + k0, &Bs[buf][sdst[1]]);               \
    }

#define DN_COMPUTE(Ab, Bb)                                                        \
    _Pragma("unroll")                                                             \
    for (int kk = 0; kk < 2; ++kk) {                                              \
        int kos = (kk * 32 + kq) ^ xorv;                                          \
        s16x8 a[4], b[2];                                                         \
        _Pragma("unroll")                                                         \
        for (int mi = 0; mi < 4; ++mi)                                            \
            a[mi] = *reinterpret_cast<const s16x8*>(&(Ab)[(wrow + mi * 16 + rl) * 64 + kos]); \
        _Pragma("unroll")                                                         \
        for (int ni = 0; ni < 2; ++ni)                                            \
            b[ni] = *reinterpret_cast<const s16x8*>(&(Bb)[(wcol + ni * 16 + rl) * 64 + kos]); \
        __builtin_amdgcn_s_setprio(1);                                            \
        _Pragma("unroll")                                                         \
        for (int mi = 0; mi < 4; ++mi)                                            \
            _Pragma("unroll")                                                     \
            for (int ni = 0; ni < 2; ++ni)                                        \
                acc[mi][ni] = __builtin_amdgcn_mfma_f32_16x16x32_bf16(a[mi], b[ni], acc[mi][ni], 0, 0, 0); \
        __builtin_amdgcn_s_setprio(0);                                            \
    }

    DN_STAGE(0, 0);
    DN_STAGE(1, 1);

    for (int t = 0; t < nk; ++t) {
        if (t + 1 < nk) asm volatile("s_waitcnt vmcnt(4)" ::: "memory");
        else            asm volatile("s_waitcnt vmcnt(0)" ::: "memory");
        __builtin_amdgcn_s_barrier();
        DN_COMPUTE(As[t & 1], Bs[t & 1]);
        __builtin_amdgcn_sched_barrier(0);
        __builtin_amdgcn_s_barrier();
        if (t + 2 < nk) DN_STAGE(t + 2, t & 1);
    }
#undef DN_COMPUTE
#undef DN_STAGE

    // epilogue: y[tok][col] += w * acc  (2 adds per element, commutative -> deterministic)
    int rbase = (lane >> 4) * 4, cbase = lane & 15;
#pragma unroll
    for (int mi = 0; mi < 4; ++mi) {
#pragma unroll
        for (int r = 0; r < 4; ++r) {
            int row = m0 + wrow + mi * 16 + rbase + r;
            if (row < ne) {
                int slot = base + row;
                int tok = list[slot];
                float w = slot_w[slot];
                float* yrow = y + (size_t)tok * DDIM + n0 + wcol + cbase;
#pragma unroll
                for (int ni = 0; ni < 2; ++ni)
                    atomicAdd(yrow + ni * 16, w * acc[mi][ni][r]);
            }
        }
    }
}

extern "C" void kernel_launch(void* const* d_in, const int* in_sizes, int n_in,
                              void* d_out, int out_size, void* d_ws, size_t ws_size,
                              hipStream_t stream) {
    const float* x  = (const float*)d_in[0];
    const float* rw = (const float*)d_in[1];
    const float* wg = (const float*)d_in[2];
    const float* wu = (const float*)d_in[3];
    const float* wd = (const float*)d_in[4];
    float* y = (float*)d_out;

    char* ws = (char*)d_ws;
    int*   r_e    = (int*)  (ws + 0);           // 2T ints
    float* r_w    = (float*)(ws + 32768);       // 2T floats
    int*   offs   = (int*)  (ws + 65600);       // 9 (padded bases)
    int*   cnt    = (int*)  (ws + 65640);       // 8 real counts
    int*   list   = (int*)  (ws + 65792);       // MAXSLOT ints
    float* slot_w = (float*)(ws + 65792 + 4 * MAXSLOT);  // MAXSLOT floats
    bf16*  xb     = (bf16*) (ws + 1048576ull);      // 8 MB
    bf16*  wguT   = (bf16*) (ws + 16777216ull);     // 64 MB  [E][2H][D] interleaved g/u
    bf16*  wdT    = (bf16*) (ws + 83886080ull);     // 32 MB  [E][D][H]
    bf16*  hbuf   = (bf16*) (ws + 117440512ull);    // 37.75 MB [MAXSLOT][H]

    // prep: wg/wu transposes + router + x-cast + y-zero (9216 blocks)
    prep_kernel<<<dim3(9216), 256, 0, stream>>>(x, rw, wg, wu, wguT, r_e, r_w, xb, y);
    binning_kernel<<<dim3(1), 1024, 0, stream>>>(r_e, r_w, offs, cnt, list, slot_w);

    // gateup GEMM + interleaved piggybacked wd transpose (8 groups of 9 GEMM + 8 wd rows)
    gateup_kernel<<<dim3(2 * HDIM / 128, 136, 1), 512, 0, stream>>>(
        xb, wguT, offs, cnt, list, hbuf, wd, wdT);
    down_kernel<<<dim3(DDIM / 128, MAXSLOT / 128, 1), 512, 0, stream>>>(
        hbuf, wdT, offs, cnt, list, slot_w, y);
}

// Round 22
// 268.293 us; speedup vs baseline: 1.0258x; 1.0258x over previous
//
#include <hip/hip_runtime.h>
#include <hip/hip_bf16.h>

#define T_TOK 4096
#define DDIM  1024
#define HDIM  2048
#define NEXP  8
#define MAXSLOT 9216   // 2T padded: each expert base 128-aligned
#define GU_YTILES 72   // MAXSLOT/128 gemm rows in gateup grid
#define WD_YROWS 64    // extra grid rows carrying wd-transpose (64*32 = 2048 blocks)

typedef __attribute__((ext_vector_type(4))) float f32x4;
typedef __attribute__((ext_vector_type(8))) short s16x8;
typedef __hip_bfloat16 bf16;

typedef const void __attribute__((address_space(1))) gvoid;
typedef void __attribute__((address_space(3))) svoid;

__device__ __forceinline__ void gload16(const void* g, void* l) {
    // async global->LDS, 16B/lane; LDS dest = wave-uniform base, HW adds lane*16
    __builtin_amdgcn_global_load_lds((gvoid*)g, (svoid*)l, 16, 0, 0);
}

// Conflict-free transpose tile swizzle (R16-proven): elem (r,c) at
// r*64 + 4*((c>>2) ^ sw(r)) + (c&3), sw(r) = ((r>>2) ^ ((r&3)<<2)) & 15.
__device__ __forceinline__ int sw_r(int r) { return ((r >> 2) ^ ((r & 3) << 2)) & 15; }

// ======== prep: wg/wu transposes + router + x-cast + y-zero (wd moved into gateup) ====
// blocks [0,8192): wg/wu transpose -> wguT interleaved
// blocks [8192,9216): router (fp64 acc top-2 softmax) + x->bf16 cast + y-zero
__global__ void prep_kernel(const float* __restrict__ x, const float* __restrict__ rw,
                            const float* __restrict__ wg, const float* __restrict__ wu,
                            bf16* __restrict__ wguT,
                            int* __restrict__ r_e, float* __restrict__ r_w,
                            bf16* __restrict__ xb, float* __restrict__ y) {
    int bid = blockIdx.x;
    int tid = threadIdx.x;

    if (bid >= 8192) {
        // ---- router + cast + y-zero ----
        int rb = bid - 8192;                   // [0,1024)
        {
            float4 z4 = {0.f, 0.f, 0.f, 0.f};
            size_t ybase = (size_t)rb * 4096 + tid * 4;
#pragma unroll
            for (int i = 0; i < 4; ++i)
                *reinterpret_cast<float4*>(y + ybase + (size_t)i * 1024) = z4;
        }
        int wave = tid >> 6, lane = tid & 63;
        int t = rb * 4 + wave;
        const float* xr = x + (size_t)t * DDIM;
        bf16* xbr = xb + (size_t)t * DDIM;
        double acc[NEXP];
#pragma unroll
        for (int e = 0; e < NEXP; ++e) acc[e] = 0.0;
#pragma unroll
        for (int c = 0; c < 4; ++c) {
            int d = c * 256 + lane * 4;
            float4 v = *reinterpret_cast<const float4*>(xr + d);
            union { ushort4 u; bf16 h[4]; } o;
            o.h[0] = __float2bfloat16(v.x);
            o.h[1] = __float2bfloat16(v.y);
            o.h[2] = __float2bfloat16(v.z);
            o.h[3] = __float2bfloat16(v.w);
            *reinterpret_cast<ushort4*>(xbr + d) = o.u;
            const float* rw0 = rw + (size_t)d * NEXP;
#pragma unroll
            for (int j = 0; j < 4; ++j) {
                float xv = (&v.x)[j];
                const float* rwr = rw0 + j * NEXP;
#pragma unroll
                for (int e = 0; e < NEXP; ++e) acc[e] += (double)xv * (double)rwr[e];
            }
        }
#pragma unroll
        for (int e = 0; e < NEXP; ++e) {
#pragma unroll
            for (int off = 32; off > 0; off >>= 1) acc[e] += __shfl_down(acc[e], off);
        }
        if (lane == 0) {
            int i0 = 0; double v0 = acc[0];
#pragma unroll
            for (int e = 1; e < NEXP; ++e) if (acc[e] > v0) { v0 = acc[e]; i0 = e; }
            int i1 = -1; double v1 = -1e300;
#pragma unroll
            for (int e = 0; e < NEXP; ++e) { if (e == i0) continue; if (acc[e] > v1) { v1 = acc[e]; i1 = e; } }
            float w0 = 1.0f / (1.0f + expf((float)(v1 - v0)));
            float w1 = 1.0f - w0;
            r_e[2*t]   = i0; r_e[2*t+1] = i1;
            r_w[2*t]   = w0; r_w[2*t+1] = w1;
        }
        return;
    }

    // ---- wg/wu transpose ----
    __shared__ __align__(16) bf16 tile[64 * 64];
    int z = bid >> 9;              // [0,16)
    int t = bid & 511;
    int which = z >> 3, e = z & 7;
    const float* inp = (which ? wu : wg) + (size_t)e * DDIM * HDIM;   // [D][H]
    bf16* outp = wguT + (size_t)e * 2 * HDIM * DDIM + (size_t)which * DDIM;
    int r0 = (t >> 5) * 64;        // 16 r-tiles over D
    int c0 = (t & 31) * 64;        // 32 c-tiles over H
#pragma unroll
    for (int i = 0; i < 4; ++i) {
        int idx = i * 256 + tid;
        int r = idx >> 4, c4 = (idx & 15) * 4;
        float4 v = *reinterpret_cast<const float4*>(inp + (size_t)(r0 + r) * HDIM + c0 + c4);
        union { ushort4 u; bf16 h[4]; } o;
        o.h[0] = __float2bfloat16(v.x);
        o.h[1] = __float2bfloat16(v.y);
        o.h[2] = __float2bfloat16(v.z);
        o.h[3] = __float2bfloat16(v.w);
        *reinterpret_cast<ushort4*>(&tile[r * 64 + 4 * ((c4 >> 2) ^ sw_r(r))]) = o.u;
    }
    __syncthreads();
#pragma unroll
    for (int i = 0; i < 4; ++i) {
        int idx = i * 256 + tid;
        int c = idx >> 4, r4 = (idx & 15) * 4;
        int g = c >> 2, ce = c & 3;
        union { ushort4 u; bf16 h[4]; } w;
#pragma unroll
        for (int j = 0; j < 4; ++j) {
            int r = r4 + j;
            w.h[j] = tile[r * 64 + 4 * (g ^ sw_r(r)) + ce];
        }
        *reinterpret_cast<ushort4*>(outp + (size_t)(c0 + c) * (2 * DDIM) + r0 + r4) = w.u;
    }
}

// ------- fused binning: count + 128-ALIGNED scan + fill, one block, 1024 thr -------
__global__ void binning_kernel(const int* __restrict__ r_e, const float* __restrict__ r_w,
                               int* __restrict__ offs, int* __restrict__ cnt,
                               int* __restrict__ list, float* __restrict__ slot_w) {
    __shared__ int scnt[NEXP], scur[NEXP], soff[NEXP + 1];
    int tid = threadIdx.x;
    if (tid < NEXP) { scnt[tid] = 0; scur[tid] = 0; }
    __syncthreads();
    for (int i = tid; i < 2 * T_TOK; i += 1024) atomicAdd(&scnt[r_e[i]], 1);
    __syncthreads();
    if (tid == 0) {
        int s = 0;
        for (int e = 0; e < NEXP; ++e) { soff[e] = s; s += (scnt[e] + 127) & ~127; }
        soff[NEXP] = s;
    }
    __syncthreads();
    if (tid < NEXP + 1) offs[tid] = soff[tid];
    if (tid < NEXP) cnt[tid] = scnt[tid];
    for (int i = tid; i < 2 * T_TOK; i += 1024) {
        int e = r_e[i];
        int pos = atomicAdd(&scur[e], 1);
        int slot = soff[e] + pos;
        list[slot] = i >> 1;
        slot_w[slot] = r_w[i];
    }
}

// expert lookup in padded slot space
__device__ __forceinline__ int find_expert(const int* offs, int slot0) {
    int e = 0;
#pragma unroll
    for (int i = 0; i < NEXP - 1; ++i) e += (offs[e + 1] <= slot0) ? 1 : 0;
    return e;
}

// ======== pass 1: gate+up GEMM  +  piggybacked wd transpose (BACK-LOADED) ========
// R20-measured best (111 us dispatch): GEMM rows first (y < GU_YTILES), wd rows
// after (y >= GU_YTILES) — transpose fills the GEMM's tail ramp-down. R21's
// interleaved variant measured WORSE (119.5 us): co-resident HBM-heavy blocks
// steal bandwidth from the GEMM critical path throughout.
__global__ __launch_bounds__(512, 2)
void gateup_kernel(const bf16* __restrict__ xb, const bf16* __restrict__ wguT,
                   const int* __restrict__ offs, const int* __restrict__ cnt,
                   const int* __restrict__ list, bf16* __restrict__ hbuf,
                   const float* __restrict__ wd, bf16* __restrict__ wdT) {
    __shared__ bf16 As[2][8192];     // GEMM: 128 rows x 64 k (16 KB/buf); wd path reuses 8 KB
    __shared__ bf16 Bs[2][8192];

    int tid = threadIdx.x;

    if (blockIdx.y >= GU_YTILES) {
        // ---- wd transpose path: 2 tiles of 64x64 per block ----
        int wdid = (blockIdx.y - GU_YTILES) * 32 + blockIdx.x;   // [0,2048)
        bf16* tile = &As[0][0];
#pragma unroll
        for (int tt = 0; tt < 2; ++tt) {
            int tb = wdid * 2 + tt;            // [0,4096)
            int e = tb >> 9;
            int t = tb & 511;
            const float* inp = wd + (size_t)e * HDIM * DDIM;     // [H][D]
            bf16* outp = wdT + (size_t)e * DDIM * HDIM;
            int r0 = (t >> 4) * 64;            // 32 r-tiles over H
            int c0 = (t & 15) * 64;            // 16 c-tiles over D
#pragma unroll
            for (int i = 0; i < 2; ++i) {
                int idx = i * 512 + tid;       // [0,1024)
                int r = idx >> 4, c4 = (idx & 15) * 4;
                float4 v = *reinterpret_cast<const float4*>(inp + (size_t)(r0 + r) * DDIM + c0 + c4);
                union { ushort4 u; bf16 h[4]; } o;
                o.h[0] = __float2bfloat16(v.x);
                o.h[1] = __float2bfloat16(v.y);
                o.h[2] = __float2bfloat16(v.z);
                o.h[3] = __float2bfloat16(v.w);
                *reinterpret_cast<ushort4*>(&tile[r * 64 + 4 * ((c4 >> 2) ^ sw_r(r))]) = o.u;
            }
            __syncthreads();
#pragma unroll
            for (int i = 0; i < 2; ++i) {
                int idx = i * 512 + tid;
                int c = idx >> 4, r4 = (idx & 15) * 4;
                int g = c >> 2, ce = c & 3;
                union { ushort4 u; bf16 h[4]; } w;
#pragma unroll
                for (int j = 0; j < 4; ++j) {
                    int r = r4 + j;
                    w.h[j] = tile[r * 64 + 4 * (g ^ sw_r(r)) + ce];
                }
                *reinterpret_cast<ushort4*>(outp + (size_t)(c0 + c) * HDIM + r0 + r4) = w.u;
            }
            __syncthreads();                   // tile buffer reuse
        }
        return;
    }

    // ---- GEMM path (R15-proven, frozen) ----
    int slot0 = blockIdx.y * 128;
    if (slot0 >= offs[NEXP]) return;
    int e = find_expert(offs, slot0);
    int base = offs[e];
    int ne = cnt[e];
    int m0 = slot0 - base;
    int n0 = blockIdx.x * 128;       // in 2H=4096 interleaved space

    int lane = tid & 63, wid = tid >> 6;       // 8 waves
    int sub = lane >> 3;                       // 0..7
    int koff = 8 * ((lane & 7) ^ sub);         // inverse-swizzled source chunk (row&7 == sub)

    const bf16* bbase = wguT + (size_t)e * (2 * HDIM) * DDIM + (size_t)n0 * DDIM;

    const bf16* aS[2]; const bf16* bS[2];
    int sdst[2];
#pragma unroll
    for (int j = 0; j < 2; ++j) {
        int q = wid + j * 8;                   // 0..15
        int row = q * 8 + sub;                 // [0,128)
        int r = m0 + row; if (r > ne - 1) r = ne - 1;   // clamp: read-only, never stored
        aS[j] = xb + (size_t)list[base + r] * DDIM + koff;
        bS[j] = bbase + (size_t)row * DDIM + koff;
        sdst[j] = q * 512;                     // wave-uniform elem offset
    }

    int rl = lane & 15, kq = 8 * (lane >> 4);
    int wrow = (wid >> 2) * 64;      // 2 M waves
    int wcol = (wid & 3) * 32;       // 4 N waves
    int xorv = (rl & 7) * 8;         // read-side swizzle

    f32x4 zero4 = {0.f, 0.f, 0.f, 0.f};
    f32x4 acc[4][2];
#pragma unroll
    for (int mi = 0; mi < 4; ++mi) { acc[mi][0] = zero4; acc[mi][1] = zero4; }

    const int nk = DDIM / 64;   // 16

#define GU_STAGE(tt, buf)                                     \
    {                                                         \
        int k0 = (tt) * 64;                                   \
        gload16(aS[0] + k0, &As[buf][sdst[0]]);               \
        gload16(aS[1] + k0, &As[buf][sdst[1]]);               \
        gload16(bS[0] + k0, &Bs[buf][sdst[0]]);               \
        gload16(bS[1] + k0, &Bs[buf][sdst[1]]);               \
    }

#define GU_COMPUTE(Ab, Bb)                                                        \
    _Pragma("unroll")                                                             \
    for (int kk = 0; kk < 2; ++kk) {                                              \
        int kos = (kk * 32 + kq) ^ xorv;                                          \
        s16x8 a[4], b[2];                                                         \
        _Pragma("unroll")                                                         \
        for (int mi = 0; mi < 4; ++mi)                                            \
            a[mi] = *reinterpret_cast<const s16x8*>(&(Ab)[(wrow + mi * 16 + rl) * 64 + kos]); \
        _Pragma("unroll")                                                         \
        for (int ni = 0; ni < 2; ++ni)                                            \
            b[ni] = *reinterpret_cast<const s16x8*>(&(Bb)[(wcol + ni * 16 + rl) * 64 + kos]); \
        __builtin_amdgcn_s_setprio(1);                                            \
        _Pragma("unroll")                                                         \
        for (int mi = 0; mi < 4; ++mi)                                            \
            _Pragma("unroll")                                                     \
            for (int ni = 0; ni < 2; ++ni)                                        \
                acc[mi][ni] = __builtin_amdgcn_mfma_f32_16x16x32_bf16(a[mi], b[ni], acc[mi][ni], 0, 0, 0); \
        __builtin_amdgcn_s_setprio(0);                                            \
    }

    GU_STAGE(0, 0);
    GU_STAGE(1, 1);

    for (int t = 0; t < nk; ++t) {
        if (t + 1 < nk) asm volatile("s_waitcnt vmcnt(4)" ::: "memory");   // tile t landed
        else            asm volatile("s_waitcnt vmcnt(0)" ::: "memory");
        __builtin_amdgcn_s_barrier();
        GU_COMPUTE(As[t & 1], Bs[t & 1]);
        __builtin_amdgcn_sched_barrier(0);
        __builtin_amdgcn_s_barrier();                 // buf[t&1] free
        if (t + 2 < nk) GU_STAGE(t + 2, t & 1);       // in flight: t+1(4) + t+2(4)
    }
#undef GU_COMPUTE
#undef GU_STAGE

    // epilogue: even col = gate, odd col = up; pair via shfl_xor(1), even lanes store.
    int rbase = (lane >> 4) * 4, cbase = lane & 15;
    bool evenlane = (lane & 1) == 0;
#pragma unroll
    for (int mi = 0; mi < 4; ++mi) {
#pragma unroll
        for (int ni = 0; ni < 2; ++ni) {
#pragma unroll
            for (int r = 0; r < 4; ++r) {
                float own = acc[mi][ni][r];
                float oth = __shfl_xor(own, 1);
                int row = m0 + wrow + mi * 16 + rbase + r;
                if (evenlane && row < ne) {
                    float g = own, u = oth;
                    float h = (g / (1.0f + expf(-g))) * u;
                    int hcol = (n0 + wcol + ni * 16 + cbase) >> 1;
                    hbuf[(size_t)(base + row) * HDIM + hcol] = __float2bfloat16(h);
                }
            }
        }
    }
}

// ======== pass 2: down GEMM, R15 structure at 128x128, BK=64 (32 iters) ========
__global__ __launch_bounds__(512, 2)
void down_kernel(const bf16* __restrict__ hbuf, const bf16* __restrict__ wdT,
                 const int* __restrict__ offs, const int* __restrict__ cnt,
                 const int* __restrict__ list, const float* __restrict__ slot_w,
                 float* __restrict__ y) {
    int slot0 = blockIdx.y * 128;
    if (slot0 >= offs[NEXP]) return;
    int e = find_expert(offs, slot0);
    int base = offs[e];
    int ne = cnt[e];
    int m0 = slot0 - base;
    int n0 = blockIdx.x * 128;   // d-tile

    __shared__ bf16 As[2][8192];
    __shared__ bf16 Bs[2][8192];

    int tid = threadIdx.x, lane = tid & 63, wid = tid >> 6;
    int sub = lane >> 3;
    int koff = 8 * ((lane & 7) ^ sub);

    const bf16* bbase = wdT + (size_t)e * DDIM * HDIM + (size_t)n0 * HDIM;

    const bf16* aS[2]; const bf16* bS[2];
    int sdst[2];
#pragma unroll
    for (int j = 0; j < 2; ++j) {
        int q = wid + j * 8;
        int row = q * 8 + sub;
        int r = m0 + row; if (r > ne - 1) r = ne - 1;
        aS[j] = hbuf + (size_t)(base + r) * HDIM + koff;
        bS[j] = bbase + (size_t)row * HDIM + koff;
        sdst[j] = q * 512;
    }

    int rl = lane & 15, kq = 8 * (lane >> 4);
    int wrow = (wid >> 2) * 64;
    int wcol = (wid & 3) * 32;
    int xorv = (rl & 7) * 8;

    f32x4 zero4 = {0.f, 0.f, 0.f, 0.f};
    f32x4 acc[4][2];
#pragma unroll
    for (int mi = 0; mi < 4; ++mi) { acc[mi][0] = zero4; acc[mi][1] = zero4; }

    const int nk = HDIM / 64;   // 32

#define DN_STAGE(tt, buf)                                     \
    {                                                         \
        int k0 = (tt) * 64;                                   \
        gload16(aS[0] + k0, &As[buf][sdst[0]]);               \
        gload16(aS[1] + k0, &As[buf][sdst[1]]);               \
        gload16(bS[0] + k0, &Bs[buf][sdst[0]]);               \
        gload16(bS[1] + k0, &Bs[buf][sdst[1]]);               \
    }

#define DN_COMPUTE(Ab, Bb)                                                        \
    _Pragma("unroll")                                                             \
    for (int kk = 0; kk < 2; ++kk) {                                              \
        int kos = (kk * 32 + kq) ^ xorv;                                          \
        s16x8 a[4], b[2];                                                         \
        _Pragma("unroll")                                                         \
        for (int mi = 0; mi < 4; ++mi)                                            \
            a[mi] = *reinterpret_cast<const s16x8*>(&(Ab)[(wrow + mi * 16 + rl) * 64 + kos]); \
        _Pragma("unroll")                                                         \
        for (int ni = 0; ni < 2; ++ni)                                            \
            b[ni] = *reinterpret_cast<const s16x8*>(&(Bb)[(wcol + ni * 16 + rl) * 64 + kos]); \
        __builtin_amdgcn_s_setprio(1);                                            \
        _Pragma("unroll")                                                         \
        for (int mi = 0; mi < 4; ++mi)                                            \
            _Pragma("unroll")                                                     \
            for (int ni = 0; ni < 2; ++ni)                                        \
                acc[mi][ni] = __builtin_amdgcn_mfma_f32_16x16x32_bf16(a[mi], b[ni], acc[mi][ni], 0, 0, 0); \
        __builtin_amdgcn_s_setprio(0);                                            \
    }

    DN_STAGE(0, 0);
    DN_STAGE(1, 1);

    for (int t = 0; t < nk; ++t) {
        if (t + 1 < nk) asm volatile("s_waitcnt vmcnt(4)" ::: "memory");
        else            asm volatile("s_waitcnt vmcnt(0)" ::: "memory");
        __builtin_amdgcn_s_barrier();
        DN_COMPUTE(As[t & 1], Bs[t & 1]);
        __builtin_amdgcn_sched_barrier(0);
        __builtin_amdgcn_s_barrier();
        if (t + 2 < nk) DN_STAGE(t + 2, t & 1);
    }
#undef DN_COMPUTE
#undef DN_STAGE

    // epilogue: y[tok][col] += w * acc  (2 adds per element, commutative -> deterministic)
    int rbase = (lane >> 4) * 4, cbase = lane & 15;
#pragma unroll
    for (int mi = 0; mi < 4; ++mi) {
#pragma unroll
        for (int r = 0; r < 4; ++r) {
            int row = m0 + wrow + mi * 16 + rbase + r;
            if (row < ne) {
                int slot = base + row;
                int tok = list[slot];
                float w = slot_w[slot];
                float* yrow = y + (size_t)tok * DDIM + n0 + wcol + cbase;
#pragma unroll
                for (int ni = 0; ni < 2; ++ni)
                    atomicAdd(yrow + ni * 16, w * acc[mi][ni][r]);
            }
        }
    }
}

extern "C" void kernel_launch(void* const* d_in, const int* in_sizes, int n_in,
                              void* d_out, int out_size, void* d_ws, size_t ws_size,
                              hipStream_t stream) {
    const float* x  = (const float*)d_in[0];
    const float* rw = (const float*)d_in[1];
    const float* wg = (const float*)d_in[2];
    const float* wu = (const float*)d_in[3];
    const float* wd = (const float*)d_in[4];
    float* y = (float*)d_out;

    char* ws = (char*)d_ws;
    int*   r_e    = (int*)  (ws + 0);           // 2T ints
    float* r_w    = (float*)(ws + 32768);       // 2T floats
    int*   offs   = (int*)  (ws + 65600);       // 9 (padded bases)
    int*   cnt    = (int*)  (ws + 65640);       // 8 real counts
    int*   list   = (int*)  (ws + 65792);       // MAXSLOT ints
    float* slot_w = (float*)(ws + 65792 + 4 * MAXSLOT);  // MAXSLOT floats
    bf16*  xb     = (bf16*) (ws + 1048576ull);      // 8 MB
    bf16*  wguT   = (bf16*) (ws + 16777216ull);     // 64 MB  [E][2H][D] interleaved g/u
    bf16*  wdT    = (bf16*) (ws + 83886080ull);     // 32 MB  [E][D][H]
    bf16*  hbuf   = (bf16*) (ws + 117440512ull);    // 37.75 MB [MAXSLOT][H]

    // prep: wg/wu transposes + router + x-cast + y-zero (9216 blocks)
    prep_kernel<<<dim3(9216), 256, 0, stream>>>(x, rw, wg, wu, wguT, r_e, r_w, xb, y);
    binning_kernel<<<dim3(1), 1024, 0, stream>>>(r_e, r_w, offs, cnt, list, slot_w);

    // gateup GEMM + piggybacked wd transpose (back-loaded rows); wdT done before down
    gateup_kernel<<<dim3(2 * HDIM / 128, GU_YTILES + WD_YROWS, 1), 512, 0, stream>>>(
        xb, wguT, offs, cnt, list, hbuf, wd, wdT);
    down_kernel<<<dim3(DDIM / 128, MAXSLOT / 128, 1), 512, 0, stream>>>(
        hbuf, wdT, offs, cnt, list, slot_w, y);
}